// Round 2
// baseline (468.305 us; speedup 1.0000x reference)
//
#include <hip/hip_runtime.h>
#include <math.h>

typedef __bf16 bf16x8 __attribute__((ext_vector_type(8)));
typedef __bf16 bf16x4 __attribute__((ext_vector_type(4)));
typedef float  f32x4  __attribute__((ext_vector_type(4)));

static __device__ __forceinline__ f32x4 mfma16(bf16x8 a, bf16x8 b, f32x4 c) {
    return __builtin_amdgcn_mfma_f32_16x16x32_bf16(a, b, c, 0, 0, 0);
}

// ---------------- Kernel A: fused QKV projection (fp32 inputs) ----------------
// X [16384 x 256] fp32 @ W_head [256 x 64] fp32
// Q/K: split-bf16 3-term MFMA (fp32-faithful) -> q,k fp32 [bh][g][64]
// V:   1-term bf16 MFMA -> v bf16 transposed [bh][dv=64][g=1024]
__global__ __launch_bounds__(256) void proj_kernel(
    const float* __restrict__ X,
    const float* __restrict__ Wq, const float* __restrict__ Wk, const float* __restrict__ Wv,
    float* __restrict__ qout, float* __restrict__ kout, __bf16* __restrict__ vT)
{
    const int rt   = blockIdx.x;   // 64-row tile of flattened [b*1024+g] (0..255)
    const int head = blockIdx.y;   // 0..7
    const int mat  = blockIdx.z;   // 0=Q 1=K 2=V

    const float* W = (mat == 0 ? Wq : (mat == 1 ? Wk : Wv)) + head * 256 * 64;
    const bool split = (mat < 2);

    // W staged hi/lo in MFMA B-fragment order: [kc(8)][t(4)][lane(64)] -> 8 bf16
    __shared__ __align__(16) __bf16 Whi[2048 * 8];   // 32 KB
    __shared__ __align__(16) __bf16 Wlo[2048 * 8];   // 32 KB

    const int tid = threadIdx.x;
    #pragma unroll
    for (int i = 0; i < 8; ++i) {
        int e = i * 256 + tid;       // 0..2047
        int kc = e >> 8, t = (e >> 6) & 3, L = e & 63;
        int qd = L >> 4, nn = L & 15;
        bf16x8 hi, lo;
        #pragma unroll
        for (int j = 0; j < 8; ++j) {
            float w = W[(kc * 32 + qd * 8 + j) * 64 + t * 16 + nn];
            __bf16 hh = (__bf16)w;
            hi[j] = hh;
            lo[j] = (__bf16)(w - (float)hh);
        }
        *(bf16x8*)&Whi[(size_t)e * 8] = hi;
        *(bf16x8*)&Wlo[(size_t)e * 8] = lo;
    }
    __syncthreads();

    const int wave = tid >> 6, lane = tid & 63, quad = lane >> 4, ln = lane & 15;
    const int grow0 = rt * 64 + wave * 16;
    const float* xrow = X + (size_t)(grow0 + ln) * 256;

    f32x4 z = {0.f, 0.f, 0.f, 0.f};
    f32x4 acc[4];
    #pragma unroll
    for (int t = 0; t < 4; ++t) acc[t] = z;

    #pragma unroll
    for (int kc = 0; kc < 8; ++kc) {
        bf16x8 ahi, alo;
        #pragma unroll
        for (int j = 0; j < 8; ++j) {
            float x = xrow[kc * 32 + quad * 8 + j];
            __bf16 hh = (__bf16)x;
            ahi[j] = hh;
            alo[j] = (__bf16)(x - (float)hh);
        }
        #pragma unroll
        for (int t = 0; t < 4; ++t) {
            bf16x8 bhi = *(const bf16x8*)&Whi[(size_t)((kc * 4 + t) * 64 + lane) * 8];
            acc[t] = mfma16(ahi, bhi, acc[t]);
            if (split) {
                bf16x8 blo = *(const bf16x8*)&Wlo[(size_t)((kc * 4 + t) * 64 + lane) * 8];
                acc[t] = mfma16(alo, bhi, acc[t]);
                acc[t] = mfma16(ahi, blo, acc[t]);
            }
        }
    }

    const int bidx = (rt * 64) >> 10;
    const int g0   = (rt * 64) & 1023;
    const int bh   = bidx * 8 + head;

    #pragma unroll
    for (int t = 0; t < 4; ++t) {
        #pragma unroll
        for (int r = 0; r < 4; ++r) {
            int row = wave * 16 + quad * 4 + r;   // within 64-row tile
            int g   = g0 + row;
            int col = t * 16 + ln;
            float val = acc[t][r];
            if (mat == 0)      qout[((size_t)bh * 1024 + g) * 64 + col] = val;
            else if (mat == 1) kout[((size_t)bh * 1024 + g) * 64 + col] = val;
            else               vT[(size_t)bh * 65536 + (size_t)col * 1024 + g] = (__bf16)val;
        }
    }
}

// ---------------- Kernel B: flash attention, split-bf16 fp32-emulated QK^T ----------------
__global__ __launch_bounds__(256) void attn_kernel(
    const float* __restrict__ qin, const float* __restrict__ kin,
    const __bf16* __restrict__ vT, const int* __restrict__ mask,
    float* __restrict__ out)
{
    const int qt = blockIdx.x;   // 0..15  (64 q-rows each)
    const int bh = blockIdx.y;   // 0..127

    __shared__ __align__(16) __bf16 k_hi[64][72];
    __shared__ __align__(16) __bf16 k_lo[64][72];
    __shared__ __align__(16) __bf16 vtl[64][72];      // [dv][m]
    __shared__ __align__(16) __bf16 pld[4][16][72];   // per-wave P relayout

    const int tid = threadIdx.x, wave = tid >> 6, lane = tid & 63;
    const int quad = lane >> 4, ln = lane & 15;

    // Q fragments, hi/lo split; rows = qt*64 + wave*16 + ln
    const float* qbase = qin + ((size_t)bh * 1024 + qt * 64 + wave * 16 + ln) * 64;
    bf16x8 qhi[2], qlo[2];
    #pragma unroll
    for (int c = 0; c < 2; ++c) {
        #pragma unroll
        for (int j = 0; j < 8; ++j) {
            float x = qbase[c * 32 + quad * 8 + j];
            __bf16 hh = (__bf16)x;
            qhi[c][j] = hh;
            qlo[c][j] = (__bf16)(x - (float)hh);
        }
    }

    f32x4 z = {0.f, 0.f, 0.f, 0.f};
    f32x4 o[4];
    #pragma unroll
    for (int t = 0; t < 4; ++t) o[t] = z;
    float mrow[4], lrow[4];
    #pragma unroll
    for (int r = 0; r < 4; ++r) { mrow[r] = -INFINITY; lrow[r] = 0.f; }

    const float scale = 0.125f;                 // 1/sqrt(64)
    const float LOG2E = 1.4426950408889634f;
    const int qrow0 = qt * 64 + wave * 16 + quad * 4;

    for (int mt = 0; mt < 16; ++mt) {
        const int m0 = mt * 64;
        // ---- stage K (fp32 -> hi/lo bf16) and V^T tile ----
        {
            const float* kb = kin + (size_t)bh * 65536 + (size_t)m0 * 64;
            #pragma unroll
            for (int i = 0; i < 4; ++i) {
                int f4 = i * 256 + tid;          // float4 id 0..1023
                int row = f4 >> 4, col = (f4 & 15) * 4;
                float4 v = *(const float4*)(kb + row * 64 + col);
                float vs[4] = {v.x, v.y, v.z, v.w};
                bf16x4 hi, lo;
                #pragma unroll
                for (int j = 0; j < 4; ++j) {
                    __bf16 hh = (__bf16)vs[j];
                    hi[j] = hh;
                    lo[j] = (__bf16)(vs[j] - (float)hh);
                }
                *(bf16x4*)&k_hi[row][col] = hi;
                *(bf16x4*)&k_lo[row][col] = lo;
            }
            const __bf16* vb = vT + (size_t)bh * 65536 + m0;
            #pragma unroll
            for (int i = 0; i < 2; ++i) {
                int e8 = i * 256 + tid;          // 8-elem chunk 0..511
                int row = e8 >> 3, col = (e8 & 7) * 8;   // row=dv
                *(bf16x8*)&vtl[row][col] = *(const bf16x8*)(vb + (size_t)row * 1024 + col);
            }
        }
        __syncthreads();

        // ---- S = Q K^T via hi*hi + lo*hi + hi*lo ----
        f32x4 s[4];
        #pragma unroll
        for (int t = 0; t < 4; ++t) {
            f32x4 acc = z;
            #pragma unroll
            for (int c = 0; c < 2; ++c) {
                bf16x8 khi = *(const bf16x8*)&k_hi[t * 16 + ln][c * 32 + quad * 8];
                bf16x8 klo = *(const bf16x8*)&k_lo[t * 16 + ln][c * 32 + quad * 8];
                acc = mfma16(qhi[c], khi, acc);
                acc = mfma16(qlo[c], khi, acc);
                acc = mfma16(qhi[c], klo, acc);
            }
            s[t] = acc;
        }

        // ---- scale + mask (mask!=0 -> disallowed) ----
        #pragma unroll
        for (int r = 0; r < 4; ++r) {
            const int* mp = mask + (size_t)(qrow0 + r) * 1024 + m0 + ln;
            #pragma unroll
            for (int t = 0; t < 4; ++t) {
                float sv = s[t][r] * scale;
                if (mp[t * 16] != 0) sv = -1e30f;
                s[t][r] = sv;
            }
        }

        // ---- online softmax (rows live in 16-lane quad groups) ----
        float pw[4][4];
        float alpha[4];
        #pragma unroll
        for (int r = 0; r < 4; ++r) {
            float tm = fmaxf(fmaxf(s[0][r], s[1][r]), fmaxf(s[2][r], s[3][r]));
            tm = fmaxf(tm, __shfl_xor(tm, 1, 64));
            tm = fmaxf(tm, __shfl_xor(tm, 2, 64));
            tm = fmaxf(tm, __shfl_xor(tm, 4, 64));
            tm = fmaxf(tm, __shfl_xor(tm, 8, 64));
            float mn = fmaxf(mrow[r], tm);
            float a  = exp2f((mrow[r] - mn) * LOG2E);
            alpha[r] = a;
            float rs = 0.f;
            #pragma unroll
            for (int t = 0; t < 4; ++t) {
                float p = exp2f((s[t][r] - mn) * LOG2E);
                pw[t][r] = p;
                rs += p;
            }
            rs += __shfl_xor(rs, 1, 64);
            rs += __shfl_xor(rs, 2, 64);
            rs += __shfl_xor(rs, 4, 64);
            rs += __shfl_xor(rs, 8, 64);
            lrow[r] = lrow[r] * a + rs;
            mrow[r] = mn;
        }

        #pragma unroll
        for (int t = 0; t < 4; ++t) {
            #pragma unroll
            for (int r = 0; r < 4; ++r) o[t][r] *= alpha[r];
        }

        // ---- P: C/D layout -> A layout via per-wave LDS ----
        #pragma unroll
        for (int t = 0; t < 4; ++t) {
            #pragma unroll
            for (int r = 0; r < 4; ++r)
                pld[wave][quad * 4 + r][t * 16 + ln] = (__bf16)pw[t][r];
        }
        // same-wave LDS RAW: make ordering explicit (DS pipe is in-order per
        // wave, and compiler must treat as may-alias, but this is ~free insurance)
        asm volatile("s_waitcnt lgkmcnt(0)" ::: "memory");

        // ---- O += P V ----
        #pragma unroll
        for (int c = 0; c < 2; ++c) {
            bf16x8 pa = *(const bf16x8*)&pld[wave][ln][c * 32 + quad * 8];
            #pragma unroll
            for (int t = 0; t < 4; ++t) {
                bf16x8 vb = *(const bf16x8*)&vtl[t * 16 + ln][c * 32 + quad * 8];
                o[t] = mfma16(pa, vb, o[t]);
            }
        }
        __syncthreads();
    }

    // ---- epilogue: O / l -> out[bh][g][dv] fp32 ----
    float* ob = out + (size_t)bh * 65536;
    #pragma unroll
    for (int r = 0; r < 4; ++r) {
        float inv = 1.0f / lrow[r];
        #pragma unroll
        for (int t = 0; t < 4; ++t)
            ob[(size_t)(qrow0 + r) * 64 + t * 16 + ln] = o[t][r] * inv;
    }
}

extern "C" void kernel_launch(void* const* d_in, const int* in_sizes, int n_in,
                              void* d_out, int out_size, void* d_ws, size_t ws_size,
                              hipStream_t stream) {
    const float* h    = (const float*)d_in[0];   // [16,1024,256] fp32
    const int*   mask = (const int*)d_in[1];     // [1024,1024] int32
    const float* Wq   = (const float*)d_in[2];   // [8,256,64] fp32
    const float* Wk   = (const float*)d_in[3];
    const float* Wv   = (const float*)d_in[4];
    float* out = (float*)d_out;                  // [16,8,1024,64] fp32

    // workspace: q fp32 (33.5 MB) + k fp32 (33.5 MB) + vT bf16 (16.8 MB) = 84 MB
    float*  q  = (float*)d_ws;
    float*  k  = q + (size_t)8388608;
    __bf16* vT = (__bf16*)(k + (size_t)8388608);

    proj_kernel<<<dim3(256, 8, 3), 256, 0, stream>>>(h, Wq, Wk, Wv, q, k, vT);
    attn_kernel<<<dim3(16, 128), 256, 0, stream>>>(q, k, vT, mask, out);
}

// Round 3
// 308.342 us; speedup vs baseline: 1.5188x; 1.5188x over previous
//
#include <hip/hip_runtime.h>
#include <math.h>

typedef __bf16 bf16x8 __attribute__((ext_vector_type(8)));
typedef float  f32x4  __attribute__((ext_vector_type(4)));

#define NEGB   (-1.4426950408889634e30f)   // -1e30 * log2(e)  (log2-domain mask value)
#define SCALE2 (0.18033688011112042f)      // (1/sqrt(64)) * log2(e), folded into q

template <int N> struct ic { static constexpr int value = N; };

static __device__ __forceinline__ f32x4 mfma16(bf16x8 a, bf16x8 b, f32x4 c) {
    return __builtin_amdgcn_mfma_f32_16x16x32_bf16(a, b, c, 0, 0, 0);
}

// async global->LDS, 16B per lane; lds dst = uniform base + lane*16
static __device__ __forceinline__ void load_lds16(const void* g, void* l) {
    __builtin_amdgcn_global_load_lds(
        (const __attribute__((address_space(1))) unsigned int*)g,
        (__attribute__((address_space(3))) unsigned int*)l, 16, 0, 0);
}

// ---------------- prep: mask -> bitmask, W -> hi/lo bf16 fragment order ----------------
// mbits[row][word16] : bit j of word w = (mask[row][w*64+j] != 0)
// W frag linear idx = ((mat*8+head)*8 + kc)*4*64 + t*64 + lane ; 8 bf16 els each (hi & lo planes)
__global__ void prep_kernel(const int* __restrict__ mask,
                            const float* __restrict__ Wq, const float* __restrict__ Wk,
                            const float* __restrict__ Wv,
                            unsigned long long* __restrict__ mbits,
                            __bf16* __restrict__ Whi_t, __bf16* __restrict__ Wlo_t)
{
    const int tid = threadIdx.x;
    if (blockIdx.x < 1024) {
        const int row = blockIdx.x, wave = tid >> 6, lane = tid & 63;
        #pragma unroll
        for (int i = 0; i < 4; ++i) {
            int word = wave * 4 + i;
            int m = mask[row * 1024 + word * 64 + lane];
            unsigned long long b = __ballot(m != 0);
            if (lane == 0) mbits[row * 16 + word] = b;
        }
    } else {
        int idx = (blockIdx.x - 1024) * 256 + tid;          // 0..49151
        int lane = idx & 63, t = (idx >> 6) & 3, kc = (idx >> 8) & 7;
        int head = (idx >> 11) & 7, mat = idx >> 14;
        int quad = lane >> 4, ln = lane & 15;
        const float* W = (mat == 0 ? Wq : (mat == 1 ? Wk : Wv)) + head * 16384;
        bf16x8 hi, lo;
        #pragma unroll
        for (int j = 0; j < 8; ++j) {
            float w = W[(kc * 32 + quad * 8 + j) * 64 + t * 16 + ln];
            __bf16 hh = (__bf16)w;
            hi[j] = hh;
            lo[j] = (__bf16)(w - (float)hh);
        }
        *(bf16x8*)(Whi_t + (size_t)idx * 8) = hi;
        *(bf16x8*)(Wlo_t + (size_t)idx * 8) = lo;
    }
}

// ---------------- projKV: K (3-term split, hi/lo tiles) and V (bf16, transposed tiles) --------
// Output tiles: [bh][mt][row64][chunk8(16B), chunk XOR-swizzled by row&7]
__global__ __launch_bounds__(256, 2) void projkv_kernel(
    const float* __restrict__ X,
    const __bf16* __restrict__ Whi_t, const __bf16* __restrict__ Wlo_t,
    unsigned char* __restrict__ khi_g, unsigned char* __restrict__ klo_g,
    unsigned char* __restrict__ vT_g)
{
    const int rt = blockIdx.x, head = blockIdx.y, z = blockIdx.z;   // z: 0=K 1=V
    const int mat = 1 + z;
    const int tid = threadIdx.x, wave = tid >> 6, lane = tid & 63;
    const int quad = lane >> 4, ln = lane & 15;

    __shared__ __align__(16) __bf16 WL[2][16384];   // 64 KB: [hi/lo][2048 frags * 8]

    // stage W fragments (hi always; lo only for K)
    const __bf16* hb = Whi_t + ((size_t)(mat * 8 + head) * 2048) * 8;
    const __bf16* lb = Wlo_t + ((size_t)(mat * 8 + head) * 2048) * 8;
    #pragma unroll
    for (int r = 0; r < 8; ++r) {
        int ch = r * 256 + wave * 64;
        load_lds16(hb + (size_t)(ch + lane) * 8, &WL[0][(size_t)ch * 8]);
        if (z == 0) load_lds16(lb + (size_t)(ch + lane) * 8, &WL[1][(size_t)ch * 8]);
    }
    __syncthreads();

    f32x4 acc[4];
    #pragma unroll
    for (int t = 0; t < 4; ++t) acc[t] = (f32x4){0.f, 0.f, 0.f, 0.f};

    const float* xr = X + ((size_t)(rt * 64 + wave * 16 + ln)) * 256;
    #pragma unroll
    for (int kc = 0; kc < 8; ++kc) {
        f32x4 xa = *(const f32x4*)(xr + kc * 32 + quad * 8);
        f32x4 xb = *(const f32x4*)(xr + kc * 32 + quad * 8 + 4);
        bf16x8 ahi, alo;
        #pragma unroll
        for (int j = 0; j < 4; ++j) {
            __bf16 h0 = (__bf16)xa[j]; ahi[j] = h0; alo[j] = (__bf16)(xa[j] - (float)h0);
            __bf16 h1 = (__bf16)xb[j]; ahi[4 + j] = h1; alo[4 + j] = (__bf16)(xb[j] - (float)h1);
        }
        #pragma unroll
        for (int t = 0; t < 4; ++t) {
            bf16x8 bhi = *(const bf16x8*)&WL[0][(size_t)((kc * 4 + t) * 64 + lane) * 8];
            acc[t] = mfma16(ahi, bhi, acc[t]);
            if (z == 0) {
                bf16x8 blo = *(const bf16x8*)&WL[1][(size_t)((kc * 4 + t) * 64 + lane) * 8];
                acc[t] = mfma16(alo, bhi, acc[t]);
                acc[t] = mfma16(ahi, blo, acc[t]);
            }
        }
    }

    const int bh = (rt >> 4) * 8 + head;
    const int mt = rt & 15;
    const size_t tb = (size_t)(bh * 16 + mt) * 8192;

    #pragma unroll
    for (int t = 0; t < 4; ++t) {
        #pragma unroll
        for (int r = 0; r < 4; ++r) {
            float val = acc[t][r];
            if (z == 0) {
                __bf16 hh = (__bf16)val;
                __bf16 ll = (__bf16)(val - (float)hh);
                int row = wave * 16 + quad * 4 + r;        // m within tile
                int lc = t * 2 + (ln >> 3);                // 16B chunk of col t*16+ln
                int sc = lc ^ (row & 7);
                size_t off = tb + (size_t)(row * 8 + sc) * 16 + (ln & 7) * 2;
                *(__bf16*)(khi_g + off) = hh;
                *(__bf16*)(klo_g + off) = ll;
            } else {
                int dvrow = t * 16 + ln;                   // dv
                int m = wave * 16 + quad * 4 + r;          // m within tile
                int lc = m >> 3;
                int sc = lc ^ (ln & 7);                    // dvrow&7 == ln&7
                size_t off = tb + (size_t)(dvrow * 8 + sc) * 16 + (m & 7) * 2;
                *(__bf16*)(vT_g + off) = (__bf16)val;
            }
        }
    }
}

// ---------------- attn: fused Q-projection + flash attention ----------------
// block = 256 thr (4 waves x 32 q-rows), BM=128, grid (8 qt, 128 bh)
__global__ __launch_bounds__(256, 2) void attn_kernel(
    const float* __restrict__ X,
    const __bf16* __restrict__ Whi_t, const __bf16* __restrict__ Wlo_t,
    const unsigned char* __restrict__ khi_g, const unsigned char* __restrict__ klo_g,
    const unsigned char* __restrict__ vT_g, const unsigned long long* __restrict__ mbits,
    float* __restrict__ out)
{
    const int qt = blockIdx.x;     // 0..7
    const int bh = blockIdx.y;     // 0..127
    const int b = bh >> 3, head = bh & 7;
    const int tid = threadIdx.x, wave = tid >> 6, lane = tid & 63;
    const int quad = lane >> 4, ln = lane & 15;

    __shared__ __align__(16) unsigned char LDSRAW[65536];
    unsigned char* lds = LDSRAW;
    // [0,24576) buf0 (khi|klo|v), [24576,49152) buf1, [49152,65536) pld (4 waves x 4 KB)
    const int pldwave = 49152 + wave * 4096;

    // ===================== Phase Q: q' = (X Wq) * SCALE2, 3-term split =====================
    f32x4 qacc[2][4];
    #pragma unroll
    for (int rg = 0; rg < 2; ++rg)
        #pragma unroll
        for (int t = 0; t < 4; ++t) qacc[rg][t] = (f32x4){0.f, 0.f, 0.f, 0.f};

    for (int half = 0; half < 2; ++half) {
        const __bf16* hb = Whi_t + ((size_t)head * 2048 + half * 1024) * 8;  // mat 0
        const __bf16* lb = Wlo_t + ((size_t)head * 2048 + half * 1024) * 8;
        #pragma unroll
        for (int j = 0; j < 4; ++j) {
            int ch = j * 256 + wave * 64;
            load_lds16(hb + (size_t)(ch + lane) * 8, lds + ch * 16);
            load_lds16(lb + (size_t)(ch + lane) * 8, lds + 16384 + ch * 16);
        }
        __syncthreads();
        #pragma unroll
        for (int rg = 0; rg < 2; ++rg) {
            const float* xr = X + ((size_t)b * 1024 + qt * 128 + wave * 32 + rg * 16 + ln) * 256;
            #pragma unroll
            for (int kcl = 0; kcl < 4; ++kcl) {
                int kc = half * 4 + kcl;
                f32x4 xa = *(const f32x4*)(xr + kc * 32 + quad * 8);
                f32x4 xb = *(const f32x4*)(xr + kc * 32 + quad * 8 + 4);
                bf16x8 ahi, alo;
                #pragma unroll
                for (int j = 0; j < 4; ++j) {
                    __bf16 h0 = (__bf16)xa[j]; ahi[j] = h0; alo[j] = (__bf16)(xa[j] - (float)h0);
                    __bf16 h1 = (__bf16)xb[j]; ahi[4 + j] = h1; alo[4 + j] = (__bf16)(xb[j] - (float)h1);
                }
                #pragma unroll
                for (int t = 0; t < 4; ++t) {
                    bf16x8 bhi = *(const bf16x8*)(lds + ((kcl * 4 + t) * 64 + lane) * 16);
                    bf16x8 blo = *(const bf16x8*)(lds + 16384 + ((kcl * 4 + t) * 64 + lane) * 16);
                    qacc[rg][t] = mfma16(ahi, bhi, qacc[rg][t]);
                    qacc[rg][t] = mfma16(alo, bhi, qacc[rg][t]);
                    qacc[rg][t] = mfma16(ahi, blo, qacc[rg][t]);
                }
            }
        }
        __syncthreads();
    }

    // C-layout -> A-layout transpose via LDS (per-wave region, 32 rows x 272B)
    #pragma unroll
    for (int rg = 0; rg < 2; ++rg)
        #pragma unroll
        for (int t = 0; t < 4; ++t) {
            qacc[rg][t] *= SCALE2;
            #pragma unroll
            for (int r = 0; r < 4; ++r)
                *(float*)(lds + wave * 8704 + (rg * 16 + quad * 4 + r) * 272 + (t * 16 + ln) * 4) =
                    qacc[rg][t][r];
        }
    bf16x8 qhi[2][2], qlo[2][2];
    #pragma unroll
    for (int rg = 0; rg < 2; ++rg)
        #pragma unroll
        for (int c = 0; c < 2; ++c) {
            f32x4 a0 = *(const f32x4*)(lds + wave * 8704 + (rg * 16 + ln) * 272 + c * 128 + quad * 32);
            f32x4 a1 = *(const f32x4*)(lds + wave * 8704 + (rg * 16 + ln) * 272 + c * 128 + quad * 32 + 16);
            #pragma unroll
            for (int j = 0; j < 4; ++j) {
                __bf16 h0 = (__bf16)a0[j]; qhi[rg][c][j] = h0; qlo[rg][c][j] = (__bf16)(a0[j] - (float)h0);
                __bf16 h1 = (__bf16)a1[j]; qhi[rg][c][4 + j] = h1; qlo[rg][c][4 + j] = (__bf16)(a1[j] - (float)h1);
            }
        }
    __syncthreads();

    // ===================== Phase A: flash loop over 16 m-tiles =====================
    // precomputed swizzled fragment addresses (bank-conflict-free reads)
    int addrA[4][2], addrP[2];
    #pragma unroll
    for (int t = 0; t < 4; ++t)
        #pragma unroll
        for (int c = 0; c < 2; ++c)
            addrA[t][c] = (t * 16 + ln) * 128 + (((c * 4 + quad) ^ (ln & 7)) << 4);
    #pragma unroll
    for (int c = 0; c < 2; ++c)
        addrP[c] = ln * 128 + (((c * 4 + quad) ^ (ln & 7)) << 4);

    f32x4 o[2][4];
    float mrow[2][4], lrow[2][4];
    #pragma unroll
    for (int rg = 0; rg < 2; ++rg)
        #pragma unroll
        for (int t = 0; t < 4; ++t) {
            o[rg][t] = (f32x4){0.f, 0.f, 0.f, 0.f};
            mrow[rg][t] = -INFINITY; lrow[rg][t] = 0.f;   // [rg][r]
        }

    const int qrow0 = qt * 128 + wave * 32 + quad * 4;

    auto stage = [&](int mt, int bufb) {
        const unsigned char* kb = khi_g + (size_t)(bh * 16 + mt) * 8192;
        const unsigned char* lb = klo_g + (size_t)(bh * 16 + mt) * 8192;
        const unsigned char* vb = vT_g + (size_t)(bh * 16 + mt) * 8192;
        #pragma unroll
        for (int j = 0; j < 2; ++j) {
            int ch = j * 256 + wave * 64;
            load_lds16(kb + (size_t)(ch + lane) * 16, lds + bufb + ch * 16);
            load_lds16(lb + (size_t)(ch + lane) * 16, lds + bufb + 8192 + ch * 16);
            load_lds16(vb + (size_t)(ch + lane) * 16, lds + bufb + 16384 + ch * 16);
        }
    };

    auto step = [&](auto bofc, int mt) {
        constexpr int BOFF = decltype(bofc)::value;
        if (mt < 15) stage(mt + 1, 24576 - BOFF);      // prefetch next tile into other buffer

        // ---- S = q' K^T (3-term, log2 domain) ----
        f32x4 s[2][4];
        #pragma unroll
        for (int rg = 0; rg < 2; ++rg)
            #pragma unroll
            for (int t = 0; t < 4; ++t) s[rg][t] = (f32x4){0.f, 0.f, 0.f, 0.f};
        #pragma unroll
        for (int t = 0; t < 4; ++t)
            #pragma unroll
            for (int c = 0; c < 2; ++c) {
                bf16x8 khi = *(const bf16x8*)(lds + BOFF + addrA[t][c]);
                bf16x8 klo = *(const bf16x8*)(lds + BOFF + 8192 + addrA[t][c]);
                #pragma unroll
                for (int rg = 0; rg < 2; ++rg) {
                    s[rg][t] = mfma16(qhi[rg][c], khi, s[rg][t]);
                    s[rg][t] = mfma16(qlo[rg][c], khi, s[rg][t]);
                    s[rg][t] = mfma16(qhi[rg][c], klo, s[rg][t]);
                }
            }

        // ---- mask (bit-packed) + online softmax + P into LDS ----
        #pragma unroll
        for (int rg = 0; rg < 2; ++rg) {
            uint2 w[4];
            #pragma unroll
            for (int r = 0; r < 4; ++r) {
                int qrow = qrow0 + rg * 16 + r;
                w[r] = *(const uint2*)((const unsigned char*)mbits + ((size_t)qrow * 16 + mt) * 8);
            }
            float pw[4][4], alpha[4];
            #pragma unroll
            for (int r = 0; r < 4; ++r) {
                float sv[4];
                #pragma unroll
                for (int t = 0; t < 4; ++t) {
                    unsigned bits = (t & 2) ? w[r].y : w[r].x;
                    unsigned bit = (bits >> ((t & 1) * 16 + ln)) & 1u;
                    sv[t] = bit ? NEGB : s[rg][t][r];
                }
                float tm = fmaxf(fmaxf(sv[0], sv[1]), fmaxf(sv[2], sv[3]));
                tm = fmaxf(tm, __shfl_xor(tm, 1));
                tm = fmaxf(tm, __shfl_xor(tm, 2));
                tm = fmaxf(tm, __shfl_xor(tm, 4));
                tm = fmaxf(tm, __shfl_xor(tm, 8));
                float mn = fmaxf(mrow[rg][r], tm);
                float a = exp2f(mrow[rg][r] - mn);
                float rs = 0.f;
                #pragma unroll
                for (int t = 0; t < 4; ++t) {
                    float p = exp2f(sv[t] - mn);
                    pw[r][t] = p; rs += p;
                }
                rs += __shfl_xor(rs, 1);
                rs += __shfl_xor(rs, 2);
                rs += __shfl_xor(rs, 4);
                rs += __shfl_xor(rs, 8);
                lrow[rg][r] = lrow[rg][r] * a + rs;
                mrow[rg][r] = mn;
                alpha[r] = a;
            }
            #pragma unroll
            for (int t = 0; t < 4; ++t)
                #pragma unroll
                for (int r = 0; r < 4; ++r) o[rg][t][r] *= alpha[r];
            // P: C-layout -> A-layout (XOR-swizzled per-wave LDS)
            #pragma unroll
            for (int t = 0; t < 4; ++t) {
                int lc16 = t * 32 + ((ln >> 3) << 4);
                #pragma unroll
                for (int r = 0; r < 4; ++r) {
                    int row = quad * 4 + r;
                    int addr = pldwave + rg * 2048 + row * 128 + (lc16 ^ ((row & 7) << 4)) + ((ln & 7) << 1);
                    *(__bf16*)(lds + addr) = (__bf16)pw[r][t];
                }
            }
        }

        // ---- O += P V ----
        #pragma unroll
        for (int c = 0; c < 2; ++c) {
            bf16x8 pa[2];
            #pragma unroll
            for (int rg = 0; rg < 2; ++rg)
                pa[rg] = *(const bf16x8*)(lds + pldwave + rg * 2048 + addrP[c]);
            #pragma unroll
            for (int t = 0; t < 4; ++t) {
                bf16x8 vb = *(const bf16x8*)(lds + BOFF + 16384 + addrA[t][c]);
                #pragma unroll
                for (int rg = 0; rg < 2; ++rg) o[rg][t] = mfma16(pa[rg], vb, o[rg][t]);
            }
        }
        __syncthreads();
    };

    stage(0, 0);
    __syncthreads();
    for (int mp = 0; mp < 8; ++mp) {
        step(ic<0>{}, 2 * mp);
        step(ic<24576>{}, 2 * mp + 1);
    }

    // ---- epilogue ----
    float* ob = out + (size_t)bh * 65536;
    #pragma unroll
    for (int rg = 0; rg < 2; ++rg)
        #pragma unroll
        for (int r = 0; r < 4; ++r) {
            float inv = 1.0f / lrow[rg][r];
            #pragma unroll
            for (int t = 0; t < 4; ++t)
                ob[(size_t)(qrow0 + rg * 16 + r) * 64 + t * 16 + ln] = o[rg][t][r] * inv;
        }
}

extern "C" void kernel_launch(void* const* d_in, const int* in_sizes, int n_in,
                              void* d_out, int out_size, void* d_ws, size_t ws_size,
                              hipStream_t stream) {
    const float* h    = (const float*)d_in[0];   // [16,1024,256] fp32
    const int*   mask = (const int*)d_in[1];     // [1024,1024] int32
    const float* Wq   = (const float*)d_in[2];   // [8,256,64] fp32
    const float* Wk   = (const float*)d_in[3];
    const float* Wv   = (const float*)d_in[4];
    float* out = (float*)d_out;                  // [16,8,1024,64] fp32

    // workspace (52.0 MB total)
    unsigned char* ws = (unsigned char*)d_ws;
    unsigned char* khi_g = ws;                                   // 16 MB
    unsigned char* klo_g = ws + 16777216;                        // 16 MB
    unsigned char* vT_g  = ws + 33554432;                        // 16 MB
    __bf16* Whi_t = (__bf16*)(ws + 50331648);                    // 768 KB
    __bf16* Wlo_t = (__bf16*)(ws + 51118080);                    // 768 KB
    unsigned long long* mbits = (unsigned long long*)(ws + 51904512); // 128 KB

    prep_kernel<<<1216, 256, 0, stream>>>(mask, Wq, Wk, Wv, mbits, Whi_t, Wlo_t);
    projkv_kernel<<<dim3(256, 8, 2), 256, 0, stream>>>(h, Whi_t, Wlo_t, khi_g, klo_g, vT_g);
    attn_kernel<<<dim3(8, 128), 256, 0, stream>>>(h, Whi_t, Wlo_t, khi_g, klo_g, vT_g, mbits, out);
}

// Round 4
// 305.372 us; speedup vs baseline: 1.5336x; 1.0097x over previous
//
#include <hip/hip_runtime.h>
#include <math.h>

typedef __bf16 bf16x8 __attribute__((ext_vector_type(8)));
typedef float  f32x4  __attribute__((ext_vector_type(4)));

#define NEGB   (-1.4426950408889634e30f)   // -1e30 * log2(e)  (log2-domain mask value)
#define SCALE2 (0.18033688011112042f)      // (1/sqrt(64)) * log2(e), folded into q

template <int N> struct ic { static constexpr int value = N; };

static __device__ __forceinline__ f32x4 mfma16(bf16x8 a, bf16x8 b, f32x4 c) {
    return __builtin_amdgcn_mfma_f32_16x16x32_bf16(a, b, c, 0, 0, 0);
}

// async global->LDS, 16B per lane; lds dst = uniform base + lane*16
static __device__ __forceinline__ void load_lds16(const void* g, void* l) {
    __builtin_amdgcn_global_load_lds(
        (const __attribute__((address_space(1))) unsigned int*)g,
        (__attribute__((address_space(3))) unsigned int*)l, 16, 0, 0);
}

// DPP row_ror (within 16-lane rows) — VALU-only cross-lane, no DS pipe
template <int CTRL>
static __device__ __forceinline__ float dppf(float x) {
    int xi = __builtin_bit_cast(int, x);
    int r = __builtin_amdgcn_update_dpp(xi, xi, CTRL, 0xf, 0xf, false);
    return __builtin_bit_cast(float, r);
}
static __device__ __forceinline__ float rowmax16(float x) {
    x = fmaxf(x, dppf<0x128>(x));   // row_ror:8
    x = fmaxf(x, dppf<0x124>(x));   // row_ror:4
    x = fmaxf(x, dppf<0x122>(x));   // row_ror:2
    x = fmaxf(x, dppf<0x121>(x));   // row_ror:1
    return x;
}
static __device__ __forceinline__ float rowsum16(float x) {
    x += dppf<0x128>(x);
    x += dppf<0x124>(x);
    x += dppf<0x122>(x);
    x += dppf<0x121>(x);
    return x;
}

// lgkm-only barrier: no vmcnt drain, keeps global_load_lds prefetch in flight
#define RAW_BARRIER() asm volatile("s_waitcnt lgkmcnt(0)\n\ts_barrier" ::: "memory")

// ---------------- prep: mask -> bitmask, W -> hi/lo bf16 fragment order ----------------
__global__ void prep_kernel(const int* __restrict__ mask,
                            const float* __restrict__ Wq, const float* __restrict__ Wk,
                            const float* __restrict__ Wv,
                            unsigned long long* __restrict__ mbits,
                            __bf16* __restrict__ Whi_t, __bf16* __restrict__ Wlo_t)
{
    const int tid = threadIdx.x;
    if (blockIdx.x < 1024) {
        const int row = blockIdx.x, wave = tid >> 6, lane = tid & 63;
        #pragma unroll
        for (int i = 0; i < 4; ++i) {
            int word = wave * 4 + i;
            int m = mask[row * 1024 + word * 64 + lane];
            unsigned long long b = __ballot(m != 0);
            if (lane == 0) mbits[row * 16 + word] = b;
        }
    } else {
        int idx = (blockIdx.x - 1024) * 256 + tid;          // 0..49151
        int lane = idx & 63, t = (idx >> 6) & 3, kc = (idx >> 8) & 7;
        int head = (idx >> 11) & 7, mat = idx >> 14;
        int quad = lane >> 4, ln = lane & 15;
        const float* W = (mat == 0 ? Wq : (mat == 1 ? Wk : Wv)) + head * 16384;
        bf16x8 hi, lo;
        #pragma unroll
        for (int j = 0; j < 8; ++j) {
            float w = W[(kc * 32 + quad * 8 + j) * 64 + t * 16 + ln];
            __bf16 hh = (__bf16)w;
            hi[j] = hh;
            lo[j] = (__bf16)(w - (float)hh);
        }
        *(bf16x8*)(Whi_t + (size_t)idx * 8) = hi;
        *(bf16x8*)(Wlo_t + (size_t)idx * 8) = lo;
    }
}

// ---------------- projKV: K (3-term split) + V (bf16, transposed), one block per (rt,head) ----
// Tiles assembled in LDS, stored with coalesced dwordx4.
__global__ __launch_bounds__(256, 2) void projkv_kernel(
    const float* __restrict__ X,
    const __bf16* __restrict__ Whi_t, const __bf16* __restrict__ Wlo_t,
    unsigned char* __restrict__ khi_g, unsigned char* __restrict__ klo_g,
    unsigned char* __restrict__ vT_g)
{
    const int rt = blockIdx.x, head = blockIdx.y;
    const int tid = threadIdx.x, wave = tid >> 6, lane = tid & 63;
    const int quad = lane >> 4, ln = lane & 15;

    __shared__ __align__(16) unsigned char SL[24576];   // khi | klo | v

    // X A-frags, hi/lo split once (rows = rt*64 + wave*16 + ln)
    const float* xr = X + ((size_t)(rt * 64 + wave * 16 + ln)) * 256;
    bf16x8 ahi[8], alo[8];
    #pragma unroll
    for (int kc = 0; kc < 8; ++kc) {
        f32x4 xa = *(const f32x4*)(xr + kc * 32 + quad * 8);
        f32x4 xb = *(const f32x4*)(xr + kc * 32 + quad * 8 + 4);
        #pragma unroll
        for (int j = 0; j < 4; ++j) {
            __bf16 h0 = (__bf16)xa[j]; ahi[kc][j] = h0; alo[kc][j] = (__bf16)(xa[j] - (float)h0);
            __bf16 h1 = (__bf16)xb[j]; ahi[kc][4 + j] = h1; alo[kc][4 + j] = (__bf16)(xb[j] - (float)h1);
        }
    }

    const __bf16* WhiK = Whi_t + ((size_t)(8 + head) * 2048) * 8;
    const __bf16* WloK = Wlo_t + ((size_t)(8 + head) * 2048) * 8;
    const __bf16* WhiV = Whi_t + ((size_t)(16 + head) * 2048) * 8;

    f32x4 kacc[4], vacc[4];
    #pragma unroll
    for (int t = 0; t < 4; ++t) { kacc[t] = (f32x4){0.f,0.f,0.f,0.f}; vacc[t] = kacc[t]; }

    #pragma unroll
    for (int kc = 0; kc < 8; ++kc) {
        #pragma unroll
        for (int t = 0; t < 4; ++t) {
            size_t fo = (size_t)((kc * 4 + t) * 64 + lane) * 8;
            bf16x8 bhiK = *(const bf16x8*)(WhiK + fo);
            bf16x8 bloK = *(const bf16x8*)(WloK + fo);
            bf16x8 bhiV = *(const bf16x8*)(WhiV + fo);
            kacc[t] = mfma16(ahi[kc], bhiK, kacc[t]);
            kacc[t] = mfma16(alo[kc], bhiK, kacc[t]);
            kacc[t] = mfma16(ahi[kc], bloK, kacc[t]);
            vacc[t] = mfma16(ahi[kc], bhiV, vacc[t]);
        }
    }

    // assemble swizzled tiles in LDS
    #pragma unroll
    for (int t = 0; t < 4; ++t) {
        #pragma unroll
        for (int r = 0; r < 4; ++r) {
            {   // K: hi/lo planes
                float val = kacc[t][r];
                __bf16 hh = (__bf16)val;
                __bf16 ll = (__bf16)(val - (float)hh);
                int row = wave * 16 + quad * 4 + r;
                int lc = t * 2 + (ln >> 3);
                int sc = lc ^ (row & 7);
                int off = (row * 8 + sc) * 16 + (ln & 7) * 2;
                *(__bf16*)(SL + off) = hh;
                *(__bf16*)(SL + 8192 + off) = ll;
            }
            {   // V transposed
                int dvrow = t * 16 + ln;
                int m = wave * 16 + quad * 4 + r;
                int lc = m >> 3;
                int sc = lc ^ (ln & 7);
                int off = (dvrow * 8 + sc) * 16 + (m & 7) * 2;
                *(__bf16*)(SL + 16384 + off) = (__bf16)vacc[t][r];
            }
        }
    }
    __syncthreads();

    const int bh = (rt >> 4) * 8 + head;
    const int mt = rt & 15;
    const size_t tb = (size_t)(bh * 16 + mt) * 8192;
    #pragma unroll
    for (int i = 0; i < 2; ++i) {
        int c = (i * 256 + tid) * 16;            // 16B chunk offset within plane
        *(uint4*)(khi_g + tb + c) = *(const uint4*)(SL + c);
        *(uint4*)(klo_g + tb + c) = *(const uint4*)(SL + 8192 + c);
        *(uint4*)(vT_g  + tb + c) = *(const uint4*)(SL + 16384 + c);
    }
}

// ---------------- attn: fused Q-projection + flash attention ----------------
// block = 256 thr (4 waves x 32 q-rows), BM=128, grid (8 qt, 128 bh), 48 KB LDS -> 3 blocks/CU
__global__ __launch_bounds__(256, 3) void attn_kernel(
    const float* __restrict__ X,
    const __bf16* __restrict__ Whi_t, const __bf16* __restrict__ Wlo_t,
    const unsigned char* __restrict__ khi_g, const unsigned char* __restrict__ klo_g,
    const unsigned char* __restrict__ vT_g, const unsigned long long* __restrict__ mbits,
    float* __restrict__ out)
{
    const int qt = blockIdx.x;     // 0..7
    const int bh = blockIdx.y;     // 0..127
    const int b = bh >> 3, head = bh & 7;
    const int tid = threadIdx.x, wave = tid >> 6, lane = tid & 63;
    const int quad = lane >> 4, ln = lane & 15;

    __shared__ __align__(16) unsigned char lds[49152];
    // buffers at 0 and 24576: [khi 8K][klo 8K][v 8K]; P overlays dead khi+klo (4 KB/wave)

    // ===================== Phase Q: q' = (X Wq) * SCALE2, 3-term split =====================
    f32x4 qacc[2][4];
    #pragma unroll
    for (int rg = 0; rg < 2; ++rg)
        #pragma unroll
        for (int t = 0; t < 4; ++t) qacc[rg][t] = (f32x4){0.f, 0.f, 0.f, 0.f};

    const __bf16* WhiQ = Whi_t + (size_t)head * 2048 * 8;
    const __bf16* WloQ = Wlo_t + (size_t)head * 2048 * 8;

    #pragma unroll
    for (int kc = 0; kc < 8; ++kc) {
        bf16x8 ahi[2], alo[2];
        #pragma unroll
        for (int rg = 0; rg < 2; ++rg) {
            const float* xr = X + ((size_t)b * 1024 + qt * 128 + wave * 32 + rg * 16 + ln) * 256;
            f32x4 xa = *(const f32x4*)(xr + kc * 32 + quad * 8);
            f32x4 xb = *(const f32x4*)(xr + kc * 32 + quad * 8 + 4);
            #pragma unroll
            for (int j = 0; j < 4; ++j) {
                __bf16 h0 = (__bf16)xa[j]; ahi[rg][j] = h0; alo[rg][j] = (__bf16)(xa[j] - (float)h0);
                __bf16 h1 = (__bf16)xb[j]; ahi[rg][4 + j] = h1; alo[rg][4 + j] = (__bf16)(xb[j] - (float)h1);
            }
        }
        #pragma unroll
        for (int t = 0; t < 4; ++t) {
            size_t fo = (size_t)((kc * 4 + t) * 64 + lane) * 8;
            bf16x8 bhi = *(const bf16x8*)(WhiQ + fo);
            bf16x8 blo = *(const bf16x8*)(WloQ + fo);
            #pragma unroll
            for (int rg = 0; rg < 2; ++rg) {
                qacc[rg][t] = mfma16(ahi[rg], bhi, qacc[rg][t]);
                qacc[rg][t] = mfma16(alo[rg], bhi, qacc[rg][t]);
                qacc[rg][t] = mfma16(ahi[rg], blo, qacc[rg][t]);
            }
        }
    }

    // C-layout -> A-layout transpose via LDS (per-wave region, 32 rows x 272B)
    #pragma unroll
    for (int rg = 0; rg < 2; ++rg)
        #pragma unroll
        for (int t = 0; t < 4; ++t) {
            qacc[rg][t] *= SCALE2;
            #pragma unroll
            for (int r = 0; r < 4; ++r)
                *(float*)(lds + wave * 8704 + (rg * 16 + quad * 4 + r) * 272 + (t * 16 + ln) * 4) =
                    qacc[rg][t][r];
        }
    bf16x8 qhi[2][2], qlo[2][2];
    #pragma unroll
    for (int rg = 0; rg < 2; ++rg)
        #pragma unroll
        for (int c = 0; c < 2; ++c) {
            f32x4 a0 = *(const f32x4*)(lds + wave * 8704 + (rg * 16 + ln) * 272 + c * 128 + quad * 32);
            f32x4 a1 = *(const f32x4*)(lds + wave * 8704 + (rg * 16 + ln) * 272 + c * 128 + quad * 32 + 16);
            #pragma unroll
            for (int j = 0; j < 4; ++j) {
                __bf16 h0 = (__bf16)a0[j]; qhi[rg][c][j] = h0; qlo[rg][c][j] = (__bf16)(a0[j] - (float)h0);
                __bf16 h1 = (__bf16)a1[j]; qhi[rg][c][4 + j] = h1; qlo[rg][c][4 + j] = (__bf16)(a1[j] - (float)h1);
            }
        }
    __syncthreads();

    // ===================== Phase A: flash loop over 16 m-tiles =====================
    int addrA[4][2], addrP[2];
    #pragma unroll
    for (int t = 0; t < 4; ++t)
        #pragma unroll
        for (int c = 0; c < 2; ++c)
            addrA[t][c] = (t * 16 + ln) * 128 + (((c * 4 + quad) ^ (ln & 7)) << 4);
    #pragma unroll
    for (int c = 0; c < 2; ++c)
        addrP[c] = ln * 128 + (((c * 4 + quad) ^ (ln & 7)) << 4);

    f32x4 o[2][4];
    float mrow[2][4], lrow[2][4];
    #pragma unroll
    for (int rg = 0; rg < 2; ++rg)
        #pragma unroll
        for (int t = 0; t < 4; ++t) {
            o[rg][t] = (f32x4){0.f, 0.f, 0.f, 0.f};
            mrow[rg][t] = -INFINITY; lrow[rg][t] = 0.f;   // [rg][r]
        }

    const int qrow0 = qt * 128 + wave * 32 + quad * 4;

    auto stage = [&](int mt, int bufb) {
        const unsigned char* kb = khi_g + (size_t)(bh * 16 + mt) * 8192;
        const unsigned char* lb = klo_g + (size_t)(bh * 16 + mt) * 8192;
        const unsigned char* vb = vT_g + (size_t)(bh * 16 + mt) * 8192;
        #pragma unroll
        for (int j = 0; j < 2; ++j) {
            int ch = j * 256 + wave * 64;
            load_lds16(kb + (size_t)(ch + lane) * 16, lds + bufb + ch * 16);
            load_lds16(lb + (size_t)(ch + lane) * 16, lds + bufb + 8192 + ch * 16);
            load_lds16(vb + (size_t)(ch + lane) * 16, lds + bufb + 16384 + ch * 16);
        }
    };

    auto step = [&](auto bofc, int mt) {
        constexpr int BOFF = decltype(bofc)::value;
        if (mt < 15) stage(mt + 1, 24576 - BOFF);      // prefetch next tile into other buffer

        // mask words early (independent loads)
        uint2 wm[2][4];
        #pragma unroll
        for (int rg = 0; rg < 2; ++rg)
            #pragma unroll
            for (int r = 0; r < 4; ++r)
                wm[rg][r] = *(const uint2*)((const unsigned char*)mbits +
                                            ((size_t)(qrow0 + rg * 16 + r) * 16 + mt) * 8);

        // ---- S = q' K^T (3-term, log2 domain) ----
        f32x4 s[2][4];
        #pragma unroll
        for (int rg = 0; rg < 2; ++rg)
            #pragma unroll
            for (int t = 0; t < 4; ++t) s[rg][t] = (f32x4){0.f, 0.f, 0.f, 0.f};
        #pragma unroll
        for (int t = 0; t < 4; ++t)
            #pragma unroll
            for (int c = 0; c < 2; ++c) {
                bf16x8 khi = *(const bf16x8*)(lds + BOFF + addrA[t][c]);
                bf16x8 klo = *(const bf16x8*)(lds + BOFF + 8192 + addrA[t][c]);
                #pragma unroll
                for (int rg = 0; rg < 2; ++rg) {
                    s[rg][t] = mfma16(qhi[rg][c], khi, s[rg][t]);
                    s[rg][t] = mfma16(qlo[rg][c], khi, s[rg][t]);
                    s[rg][t] = mfma16(qhi[rg][c], klo, s[rg][t]);
                }
            }

        // all waves done reading khi/klo -> safe to overlay P (keep prefetch in flight)
        RAW_BARRIER();

        // ---- mask + online softmax (DPP reductions) + P into dead khi/klo ----
        #pragma unroll
        for (int rg = 0; rg < 2; ++rg) {
            float pw[4][4], alpha[4];
            #pragma unroll
            for (int r = 0; r < 4; ++r) {
                float sv[4];
                #pragma unroll
                for (int t = 0; t < 4; ++t) {
                    unsigned bits = (t & 2) ? wm[rg][r].y : wm[rg][r].x;
                    float bit = (float)((bits >> ((t & 1) * 16 + ln)) & 1u);
                    sv[t] = fmaf(bit, NEGB, s[rg][t][r]);
                }
                float tm = fmaxf(fmaxf(sv[0], sv[1]), fmaxf(sv[2], sv[3]));
                tm = rowmax16(tm);
                float mn = fmaxf(mrow[rg][r], tm);
                float a = __builtin_amdgcn_exp2f(mrow[rg][r] - mn);
                float rs = 0.f;
                #pragma unroll
                for (int t = 0; t < 4; ++t) {
                    float p = __builtin_amdgcn_exp2f(sv[t] - mn);
                    pw[r][t] = p; rs += p;
                }
                rs = rowsum16(rs);
                lrow[rg][r] = lrow[rg][r] * a + rs;
                mrow[rg][r] = mn;
                alpha[r] = a;
            }
            #pragma unroll
            for (int t = 0; t < 4; ++t)
                #pragma unroll
                for (int r = 0; r < 4; ++r) o[rg][t][r] *= alpha[r];
            // P: C-layout -> A-layout (XOR-swizzled, per-wave 4 KB in dead khi/klo)
            #pragma unroll
            for (int t = 0; t < 4; ++t) {
                int lc16 = t * 32 + ((ln >> 3) << 4);
                #pragma unroll
                for (int r = 0; r < 4; ++r) {
                    int row = quad * 4 + r;
                    int addr = BOFF + wave * 4096 + rg * 2048 + row * 128 +
                               (lc16 ^ ((row & 7) << 4)) + ((ln & 7) << 1);
                    *(__bf16*)(lds + addr) = (__bf16)pw[r][t];
                }
            }
        }
        // same-wave P RAW ordering
        asm volatile("s_waitcnt lgkmcnt(0)" ::: "memory");

        // ---- O += P V ----
        #pragma unroll
        for (int c = 0; c < 2; ++c) {
            bf16x8 pa[2];
            #pragma unroll
            for (int rg = 0; rg < 2; ++rg)
                pa[rg] = *(const bf16x8*)(lds + BOFF + wave * 4096 + rg * 2048 + addrP[c]);
            #pragma unroll
            for (int t = 0; t < 4; ++t) {
                bf16x8 vb = *(const bf16x8*)(lds + BOFF + 16384 + addrA[t][c]);
                #pragma unroll
                for (int rg = 0; rg < 2; ++rg) o[rg][t] = mfma16(pa[rg], vb, o[rg][t]);
            }
        }
        __syncthreads();   // drains prefetch (vmcnt0) + P reads; next tile ready
    };

    stage(0, 0);
    __syncthreads();
    for (int mp = 0; mp < 8; ++mp) {
        step(ic<0>{}, 2 * mp);
        step(ic<24576>{}, 2 * mp + 1);
    }

    // ---- epilogue ----
    float* ob = out + (size_t)bh * 65536;
    #pragma unroll
    for (int rg = 0; rg < 2; ++rg)
        #pragma unroll
        for (int r = 0; r < 4; ++r) {
            float inv = 1.0f / lrow[rg][r];
            #pragma unroll
            for (int t = 0; t < 4; ++t)
                ob[(size_t)(qrow0 + rg * 16 + r) * 64 + t * 16 + ln] = o[rg][t][r] * inv;
        }
}

extern "C" void kernel_launch(void* const* d_in, const int* in_sizes, int n_in,
                              void* d_out, int out_size, void* d_ws, size_t ws_size,
                              hipStream_t stream) {
    const float* h    = (const float*)d_in[0];   // [16,1024,256] fp32
    const int*   mask = (const int*)d_in[1];     // [1024,1024] int32
    const float* Wq   = (const float*)d_in[2];   // [8,256,64] fp32
    const float* Wk   = (const float*)d_in[3];
    const float* Wv   = (const float*)d_in[4];
    float* out = (float*)d_out;                  // [16,8,1024,64] fp32

    unsigned char* ws = (unsigned char*)d_ws;
    unsigned char* khi_g = ws;                                   // 16 MB
    unsigned char* klo_g = ws + 16777216;                        // 16 MB
    unsigned char* vT_g  = ws + 33554432;                        // 16 MB
    __bf16* Whi_t = (__bf16*)(ws + 50331648);                    // 768 KB
    __bf16* Wlo_t = (__bf16*)(ws + 51118080);                    // 768 KB
    unsigned long long* mbits = (unsigned long long*)(ws + 51904512); // 128 KB

    prep_kernel<<<1216, 256, 0, stream>>>(mask, Wq, Wk, Wv, mbits, Whi_t, Wlo_t);
    projkv_kernel<<<dim3(256, 8), 256, 0, stream>>>(h, Whi_t, Wlo_t, khi_g, klo_g, vT_g);
    attn_kernel<<<dim3(8, 128), 256, 0, stream>>>(h, Whi_t, Wlo_t, khi_g, klo_g, vT_g, mbits, out);
}

// Round 5
// 248.366 us; speedup vs baseline: 1.8855x; 1.2295x over previous
//
#include <hip/hip_runtime.h>
#include <math.h>

typedef __bf16 bf16x8 __attribute__((ext_vector_type(8)));
typedef float  f32x4  __attribute__((ext_vector_type(4)));

#define NEGB   (-1.4426950408889634e30f)   // -1e30 * log2(e)  (log2-domain mask value)
#define SCALE2 (0.18033688011112042f)      // (1/sqrt(64)) * log2(e), folded into q

template <int N> struct ic { static constexpr int value = N; };

static __device__ __forceinline__ f32x4 mfma16(bf16x8 a, bf16x8 b, f32x4 c) {
    return __builtin_amdgcn_mfma_f32_16x16x32_bf16(a, b, c, 0, 0, 0);
}

// async global->LDS, 16B per lane; lds dst = uniform base + lane*16
static __device__ __forceinline__ void load_lds16(const void* g, void* l) {
    __builtin_amdgcn_global_load_lds(
        (const __attribute__((address_space(1))) unsigned int*)g,
        (__attribute__((address_space(3))) unsigned int*)l, 16, 0, 0);
}

// DPP row_ror (within 16-lane rows) — VALU-only cross-lane, no DS pipe
template <int CTRL>
static __device__ __forceinline__ float dppf(float x) {
    int xi = __builtin_bit_cast(int, x);
    int r = __builtin_amdgcn_update_dpp(xi, xi, CTRL, 0xf, 0xf, false);
    return __builtin_bit_cast(float, r);
}
static __device__ __forceinline__ float rowmax16(float x) {
    x = fmaxf(x, dppf<0x128>(x));   // row_ror:8
    x = fmaxf(x, dppf<0x124>(x));   // row_ror:4
    x = fmaxf(x, dppf<0x122>(x));   // row_ror:2
    x = fmaxf(x, dppf<0x121>(x));   // row_ror:1
    return x;
}
static __device__ __forceinline__ float rowsum16(float x) {
    x += dppf<0x128>(x);
    x += dppf<0x124>(x);
    x += dppf<0x122>(x);
    x += dppf<0x121>(x);
    return x;
}

// lgkm-only barrier: no vmcnt drain, keeps global_load_lds prefetch in flight
#define RAW_BARRIER() asm volatile("s_waitcnt lgkmcnt(0)\n\ts_barrier" ::: "memory")

// ---------------- prep: mask -> bitmask, W -> hi/lo bf16 fragment order ----------------
__global__ void prep_kernel(const int* __restrict__ mask,
                            const float* __restrict__ Wq, const float* __restrict__ Wk,
                            const float* __restrict__ Wv,
                            unsigned long long* __restrict__ mbits,
                            __bf16* __restrict__ Whi_t, __bf16* __restrict__ Wlo_t)
{
    const int tid = threadIdx.x;
    if (blockIdx.x < 1024) {
        const int row = blockIdx.x, wave = tid >> 6, lane = tid & 63;
        #pragma unroll
        for (int i = 0; i < 4; ++i) {
            int word = wave * 4 + i;
            int m = mask[row * 1024 + word * 64 + lane];
            unsigned long long b = __ballot(m != 0);
            if (lane == 0) mbits[row * 16 + word] = b;
        }
    } else {
        int idx = (blockIdx.x - 1024) * 256 + tid;          // 0..49151
        int lane = idx & 63, t = (idx >> 6) & 3, kc = (idx >> 8) & 7;
        int head = (idx >> 11) & 7, mat = idx >> 14;
        int quad = lane >> 4, ln = lane & 15;
        const float* W = (mat == 0 ? Wq : (mat == 1 ? Wk : Wv)) + head * 16384;
        bf16x8 hi, lo;
        #pragma unroll
        for (int j = 0; j < 8; ++j) {
            float w = W[(kc * 32 + quad * 8 + j) * 64 + t * 16 + ln];
            __bf16 hh = (__bf16)w;
            hi[j] = hh;
            lo[j] = (__bf16)(w - (float)hh);
        }
        *(bf16x8*)(Whi_t + (size_t)idx * 8) = hi;
        *(bf16x8*)(Wlo_t + (size_t)idx * 8) = lo;
    }
}

// ---------------- projKV: K (3-term split) + V (bf16, transposed) ----------------
// grid (8 head FAST, 256 rt SLOW): the 8 blocks sharing X rows are dispatch-adjacent
// -> X fetched from HBM once, served from L3 to the other 7.
__global__ __launch_bounds__(256, 2) void projkv_kernel(
    const float* __restrict__ X,
    const __bf16* __restrict__ Whi_t, const __bf16* __restrict__ Wlo_t,
    unsigned char* __restrict__ khi_g, unsigned char* __restrict__ klo_g,
    unsigned char* __restrict__ vT_g)
{
    const int head = blockIdx.x, rt = blockIdx.y;
    const int tid = threadIdx.x, wave = tid >> 6, lane = tid & 63;
    const int quad = lane >> 4, ln = lane & 15;

    __shared__ __align__(16) unsigned char SL[24576];   // khi | klo | v

    // X A-frags, hi/lo split once (rows = rt*64 + wave*16 + ln)
    const float* xr = X + ((size_t)(rt * 64 + wave * 16 + ln)) * 256;
    bf16x8 ahi[8], alo[8];
    #pragma unroll
    for (int kc = 0; kc < 8; ++kc) {
        f32x4 xa = *(const f32x4*)(xr + kc * 32 + quad * 8);
        f32x4 xb = *(const f32x4*)(xr + kc * 32 + quad * 8 + 4);
        #pragma unroll
        for (int j = 0; j < 4; ++j) {
            __bf16 h0 = (__bf16)xa[j]; ahi[kc][j] = h0; alo[kc][j] = (__bf16)(xa[j] - (float)h0);
            __bf16 h1 = (__bf16)xb[j]; ahi[kc][4 + j] = h1; alo[kc][4 + j] = (__bf16)(xb[j] - (float)h1);
        }
    }

    const __bf16* WhiK = Whi_t + ((size_t)(8 + head) * 2048) * 8;
    const __bf16* WloK = Wlo_t + ((size_t)(8 + head) * 2048) * 8;
    const __bf16* WhiV = Whi_t + ((size_t)(16 + head) * 2048) * 8;

    f32x4 kacc[4], vacc[4];
    #pragma unroll
    for (int t = 0; t < 4; ++t) { kacc[t] = (f32x4){0.f,0.f,0.f,0.f}; vacc[t] = kacc[t]; }

    #pragma unroll
    for (int kc = 0; kc < 8; ++kc) {
        #pragma unroll
        for (int t = 0; t < 4; ++t) {
            size_t fo = (size_t)((kc * 4 + t) * 64 + lane) * 8;
            bf16x8 bhiK = *(const bf16x8*)(WhiK + fo);
            bf16x8 bloK = *(const bf16x8*)(WloK + fo);
            bf16x8 bhiV = *(const bf16x8*)(WhiV + fo);
            kacc[t] = mfma16(ahi[kc], bhiK, kacc[t]);
            kacc[t] = mfma16(alo[kc], bhiK, kacc[t]);
            kacc[t] = mfma16(ahi[kc], bloK, kacc[t]);
            vacc[t] = mfma16(ahi[kc], bhiV, vacc[t]);
        }
    }

    // assemble swizzled tiles in LDS
    #pragma unroll
    for (int t = 0; t < 4; ++t) {
        #pragma unroll
        for (int r = 0; r < 4; ++r) {
            {   // K: hi/lo planes
                float val = kacc[t][r];
                __bf16 hh = (__bf16)val;
                __bf16 ll = (__bf16)(val - (float)hh);
                int row = wave * 16 + quad * 4 + r;
                int lc = t * 2 + (ln >> 3);
                int sc = lc ^ (row & 7);
                int off = (row * 8 + sc) * 16 + (ln & 7) * 2;
                *(__bf16*)(SL + off) = hh;
                *(__bf16*)(SL + 8192 + off) = ll;
            }
            {   // V transposed
                int dvrow = t * 16 + ln;
                int m = wave * 16 + quad * 4 + r;
                int lc = m >> 3;
                int sc = lc ^ (ln & 7);
                int off = (dvrow * 8 + sc) * 16 + (m & 7) * 2;
                *(__bf16*)(SL + 16384 + off) = (__bf16)vacc[t][r];
            }
        }
    }
    __syncthreads();

    const int bh = (rt >> 4) * 8 + head;
    const int mt = rt & 15;
    const size_t tb = (size_t)(bh * 16 + mt) * 8192;
    #pragma unroll
    for (int i = 0; i < 2; ++i) {
        int c = (i * 256 + tid) * 16;            // 16B chunk offset within plane
        *(uint4*)(khi_g + tb + c) = *(const uint4*)(SL + c);
        *(uint4*)(klo_g + tb + c) = *(const uint4*)(SL + 8192 + c);
        *(uint4*)(vT_g  + tb + c) = *(const uint4*)(SL + 16384 + c);
    }
}

// ---------------- attn: fused Q-projection + flash attention ----------------
// block = 256 thr (4 waves x 32 q-rows), BM=128, grid (128 bh FAST, 8 qt SLOW)
// 48 KB LDS; launch_bounds(256,2): no VGPR cap -> no spill; HW occ = min(VGPR, LDS=3 blk)
__global__ __launch_bounds__(256, 2) void attn_kernel(
    const float* __restrict__ X,
    const __bf16* __restrict__ Whi_t, const __bf16* __restrict__ Wlo_t,
    const unsigned char* __restrict__ khi_g, const unsigned char* __restrict__ klo_g,
    const unsigned char* __restrict__ vT_g, const unsigned long long* __restrict__ mbits,
    float* __restrict__ out)
{
    const int qt = blockIdx.y;     // 0..7
    const int bh = blockIdx.x;     // 0..127 (adjacent blocks share X rows across heads)
    const int b = bh >> 3, head = bh & 7;
    const int tid = threadIdx.x, wave = tid >> 6, lane = tid & 63;
    const int quad = lane >> 4, ln = lane & 15;

    __shared__ __align__(16) unsigned char lds[49152];
    // buffers at 0 and 24576: [khi 8K][klo 8K][v 8K]; P overlays dead khi+klo (4 KB/wave)

    // ===================== Phase Q: q' = (X Wq) * SCALE2, 3-term split =====================
    f32x4 qacc[2][4];
    #pragma unroll
    for (int rg = 0; rg < 2; ++rg)
        #pragma unroll
        for (int t = 0; t < 4; ++t) qacc[rg][t] = (f32x4){0.f, 0.f, 0.f, 0.f};

    const __bf16* WhiQ = Whi_t + (size_t)head * 2048 * 8;
    const __bf16* WloQ = Wlo_t + (size_t)head * 2048 * 8;

    #pragma unroll
    for (int kc = 0; kc < 8; ++kc) {
        bf16x8 ahi[2], alo[2];
        #pragma unroll
        for (int rg = 0; rg < 2; ++rg) {
            const float* xr = X + ((size_t)b * 1024 + qt * 128 + wave * 32 + rg * 16 + ln) * 256;
            f32x4 xa = *(const f32x4*)(xr + kc * 32 + quad * 8);
            f32x4 xb = *(const f32x4*)(xr + kc * 32 + quad * 8 + 4);
            #pragma unroll
            for (int j = 0; j < 4; ++j) {
                __bf16 h0 = (__bf16)xa[j]; ahi[rg][j] = h0; alo[rg][j] = (__bf16)(xa[j] - (float)h0);
                __bf16 h1 = (__bf16)xb[j]; ahi[rg][4 + j] = h1; alo[rg][4 + j] = (__bf16)(xb[j] - (float)h1);
            }
        }
        #pragma unroll
        for (int t = 0; t < 4; ++t) {
            size_t fo = (size_t)((kc * 4 + t) * 64 + lane) * 8;
            bf16x8 bhi = *(const bf16x8*)(WhiQ + fo);
            bf16x8 blo = *(const bf16x8*)(WloQ + fo);
            #pragma unroll
            for (int rg = 0; rg < 2; ++rg) {
                qacc[rg][t] = mfma16(ahi[rg], bhi, qacc[rg][t]);
                qacc[rg][t] = mfma16(alo[rg], bhi, qacc[rg][t]);
                qacc[rg][t] = mfma16(ahi[rg], blo, qacc[rg][t]);
            }
        }
    }

    // C-layout -> A-layout transpose via LDS (per-wave region, 32 rows x 272B)
    #pragma unroll
    for (int rg = 0; rg < 2; ++rg)
        #pragma unroll
        for (int t = 0; t < 4; ++t) {
            qacc[rg][t] *= SCALE2;
            #pragma unroll
            for (int r = 0; r < 4; ++r)
                *(float*)(lds + wave * 8704 + (rg * 16 + quad * 4 + r) * 272 + (t * 16 + ln) * 4) =
                    qacc[rg][t][r];
        }
    bf16x8 qhi[2][2], qlo[2][2];
    #pragma unroll
    for (int rg = 0; rg < 2; ++rg)
        #pragma unroll
        for (int c = 0; c < 2; ++c) {
            f32x4 a0 = *(const f32x4*)(lds + wave * 8704 + (rg * 16 + ln) * 272 + c * 128 + quad * 32);
            f32x4 a1 = *(const f32x4*)(lds + wave * 8704 + (rg * 16 + ln) * 272 + c * 128 + quad * 32 + 16);
            #pragma unroll
            for (int j = 0; j < 4; ++j) {
                __bf16 h0 = (__bf16)a0[j]; qhi[rg][c][j] = h0; qlo[rg][c][j] = (__bf16)(a0[j] - (float)h0);
                __bf16 h1 = (__bf16)a1[j]; qhi[rg][c][4 + j] = h1; qlo[rg][c][4 + j] = (__bf16)(a1[j] - (float)h1);
            }
        }
    __syncthreads();

    // ===================== Phase A: flash loop over 16 m-tiles =====================
    int addrA[4][2], addrP[2];
    #pragma unroll
    for (int t = 0; t < 4; ++t)
        #pragma unroll
        for (int c = 0; c < 2; ++c)
            addrA[t][c] = (t * 16 + ln) * 128 + (((c * 4 + quad) ^ (ln & 7)) << 4);
    #pragma unroll
    for (int c = 0; c < 2; ++c)
        addrP[c] = ln * 128 + (((c * 4 + quad) ^ (ln & 7)) << 4);

    f32x4 o[2][4];
    float mrow[2][4], lrow[2][4];
    #pragma unroll
    for (int rg = 0; rg < 2; ++rg)
        #pragma unroll
        for (int t = 0; t < 4; ++t) {
            o[rg][t] = (f32x4){0.f, 0.f, 0.f, 0.f};
            mrow[rg][t] = -INFINITY; lrow[rg][t] = 0.f;   // [rg][r]
        }

    const int qrow0 = qt * 128 + wave * 32 + quad * 4;

    auto stage = [&](int mt, int bufb) {
        const unsigned char* kb = khi_g + (size_t)(bh * 16 + mt) * 8192;
        const unsigned char* lb = klo_g + (size_t)(bh * 16 + mt) * 8192;
        const unsigned char* vb = vT_g + (size_t)(bh * 16 + mt) * 8192;
        #pragma unroll
        for (int j = 0; j < 2; ++j) {
            int ch = j * 256 + wave * 64;
            load_lds16(kb + (size_t)(ch + lane) * 16, lds + bufb + ch * 16);
            load_lds16(lb + (size_t)(ch + lane) * 16, lds + bufb + 8192 + ch * 16);
            load_lds16(vb + (size_t)(ch + lane) * 16, lds + bufb + 16384 + ch * 16);
        }
    };

    auto step = [&](auto bofc, int mt) {
        constexpr int BOFF = decltype(bofc)::value;
        if (mt < 15) stage(mt + 1, 24576 - BOFF);      // prefetch next tile into other buffer

        // mask words early (independent loads)
        uint2 wm[2][4];
        #pragma unroll
        for (int rg = 0; rg < 2; ++rg)
            #pragma unroll
            for (int r = 0; r < 4; ++r)
                wm[rg][r] = *(const uint2*)((const unsigned char*)mbits +
                                            ((size_t)(qrow0 + rg * 16 + r) * 16 + mt) * 8);

        // ---- S = q' K^T (3-term, log2 domain) ----
        f32x4 s[2][4];
        #pragma unroll
        for (int rg = 0; rg < 2; ++rg)
            #pragma unroll
            for (int t = 0; t < 4; ++t) s[rg][t] = (f32x4){0.f, 0.f, 0.f, 0.f};
        #pragma unroll
        for (int t = 0; t < 4; ++t)
            #pragma unroll
            for (int c = 0; c < 2; ++c) {
                bf16x8 khi = *(const bf16x8*)(lds + BOFF + addrA[t][c]);
                bf16x8 klo = *(const bf16x8*)(lds + BOFF + 8192 + addrA[t][c]);
                #pragma unroll
                for (int rg = 0; rg < 2; ++rg) {
                    s[rg][t] = mfma16(qhi[rg][c], khi, s[rg][t]);
                    s[rg][t] = mfma16(qlo[rg][c], khi, s[rg][t]);
                    s[rg][t] = mfma16(qhi[rg][c], klo, s[rg][t]);
                }
            }

        // all waves done reading khi/klo -> safe to overlay P (keep prefetch in flight)
        RAW_BARRIER();

        // ---- mask + online softmax (DPP reductions) + P into dead khi/klo ----
        #pragma unroll
        for (int rg = 0; rg < 2; ++rg) {
            float pw[4][4], alpha[4];
            #pragma unroll
            for (int r = 0; r < 4; ++r) {
                float sv[4];
                #pragma unroll
                for (int t = 0; t < 4; ++t) {
                    unsigned bits = (t & 2) ? wm[rg][r].y : wm[rg][r].x;
                    float bit = (float)((bits >> ((t & 1) * 16 + ln)) & 1u);
                    sv[t] = fmaf(bit, NEGB, s[rg][t][r]);
                }
                float tm = fmaxf(fmaxf(sv[0], sv[1]), fmaxf(sv[2], sv[3]));
                tm = rowmax16(tm);
                float mn = fmaxf(mrow[rg][r], tm);
                float a = __builtin_amdgcn_exp2f(mrow[rg][r] - mn);
                float rs = 0.f;
                #pragma unroll
                for (int t = 0; t < 4; ++t) {
                    float p = __builtin_amdgcn_exp2f(sv[t] - mn);
                    pw[r][t] = p; rs += p;
                }
                rs = rowsum16(rs);
                lrow[rg][r] = lrow[rg][r] * a + rs;
                mrow[rg][r] = mn;
                alpha[r] = a;
            }
            #pragma unroll
            for (int t = 0; t < 4; ++t)
                #pragma unroll
                for (int r = 0; r < 4; ++r) o[rg][t][r] *= alpha[r];
            // P: C-layout -> A-layout (XOR-swizzled, per-wave 4 KB in dead khi/klo)
            #pragma unroll
            for (int t = 0; t < 4; ++t) {
                int lc16 = t * 32 + ((ln >> 3) << 4);
                #pragma unroll
                for (int r = 0; r < 4; ++r) {
                    int row = quad * 4 + r;
                    int addr = BOFF + wave * 4096 + rg * 2048 + row * 128 +
                               (lc16 ^ ((row & 7) << 4)) + ((ln & 7) << 1);
                    *(__bf16*)(lds + addr) = (__bf16)pw[r][t];
                }
            }
        }
        // same-wave P RAW ordering
        asm volatile("s_waitcnt lgkmcnt(0)" ::: "memory");

        // ---- O += P V ----
        #pragma unroll
        for (int c = 0; c < 2; ++c) {
            bf16x8 pa[2];
            #pragma unroll
            for (int rg = 0; rg < 2; ++rg)
                pa[rg] = *(const bf16x8*)(lds + BOFF + wave * 4096 + rg * 2048 + addrP[c]);
            #pragma unroll
            for (int t = 0; t < 4; ++t) {
                bf16x8 vb = *(const bf16x8*)(lds + BOFF + 16384 + addrA[t][c]);
                #pragma unroll
                for (int rg = 0; rg < 2; ++rg) o[rg][t] = mfma16(pa[rg], vb, o[rg][t]);
            }
        }
        __syncthreads();   // drains prefetch (vmcnt0) + P reads; next tile ready
    };

    stage(0, 0);
    __syncthreads();
    for (int mp = 0; mp < 8; ++mp) {
        step(ic<0>{}, 2 * mp);
        step(ic<24576>{}, 2 * mp + 1);
    }

    // ---- epilogue ----
    float* ob = out + (size_t)bh * 65536;
    #pragma unroll
    for (int rg = 0; rg < 2; ++rg)
        #pragma unroll
        for (int r = 0; r < 4; ++r) {
            float inv = 1.0f / lrow[rg][r];
            #pragma unroll
            for (int t = 0; t < 4; ++t)
                ob[(size_t)(qrow0 + rg * 16 + r) * 64 + t * 16 + ln] = o[rg][t][r] * inv;
        }
}

extern "C" void kernel_launch(void* const* d_in, const int* in_sizes, int n_in,
                              void* d_out, int out_size, void* d_ws, size_t ws_size,
                              hipStream_t stream) {
    const float* h    = (const float*)d_in[0];   // [16,1024,256] fp32
    const int*   mask = (const int*)d_in[1];     // [1024,1024] int32
    const float* Wq   = (const float*)d_in[2];   // [8,256,64] fp32
    const float* Wk   = (const float*)d_in[3];
    const float* Wv   = (const float*)d_in[4];
    float* out = (float*)d_out;                  // [16,8,1024,64] fp32

    unsigned char* ws = (unsigned char*)d_ws;
    unsigned char* khi_g = ws;                                   // 16 MB
    unsigned char* klo_g = ws + 16777216;                        // 16 MB
    unsigned char* vT_g  = ws + 33554432;                        // 16 MB
    __bf16* Whi_t = (__bf16*)(ws + 50331648);                    // 768 KB
    __bf16* Wlo_t = (__bf16*)(ws + 51118080);                    // 768 KB
    unsigned long long* mbits = (unsigned long long*)(ws + 51904512); // 128 KB

    prep_kernel<<<1216, 256, 0, stream>>>(mask, Wq, Wk, Wv, mbits, Whi_t, Wlo_t);
    projkv_kernel<<<dim3(8, 256), 256, 0, stream>>>(h, Whi_t, Wlo_t, khi_g, klo_g, vT_g);
    attn_kernel<<<dim3(128, 8), 256, 0, stream>>>(h, Whi_t, Wlo_t, khi_g, klo_g, vT_g, mbits, out);
}